// Round 1
// 88.039 us; speedup vs baseline: 1.4793x; 1.4793x over previous
//
#include <hip/hip_runtime.h>

// SoftMinLayer via MFMA: cross[i,j,k] = <window(i,j), shapelet k> is a
// 974x50 @ 50x100 GEMM per sequence (A = Hankel of x row). fp32 has no MFMA
// on CDNA4, so use bf16 hi/lo split: cross ~= xh*sh + xh*sl + xl*sh via
// mfma_f32_16x16x32_bf16 (error ~2^-18 rel -> D err ~1e-6, negligible).
// sq_win and ssq computed exactly in fp32; softmin epilogue on VALU.
//
// A-fragment needs per-lane 8 consecutive bf16 starting at index == lane (mod 8)
// -> 8 element-shifted LDS copies of the bf16 row give aligned ds_read_b128.
// B hi-frags in registers (reused 2x), B lo-frags in lane-strided LDS.
// D layout (verified, guide §3): col = lane&15 (k), row = (lane>>4)*4+reg (j).

#define N_SEQ   512
#define Q_LEN   1024
#define K_SH    100
#define L_SH    50
#define J_WIN   974              // Q - L
#define NTILE   7                // ceil(100/16) k-tiles
#define MTILES  61               // ceil(974/16) j-tiles (976 rows incl 2 pad)
#define ALPHA_F (-100.0f)
#define SKIP_T  0.5f             // exp(-100*0.5)=2e-22: negligible vs S>=1
#define RINV_L  0.02f            // 1/50
#define PAD_SQ  4e31f            // sq_win pad -> dv ~ 8e29 >> any real D

#define CPR     1064             // region stride (elems) for shifted copies

typedef short  short8 __attribute__((ext_vector_type(8)));
typedef float  f32x4  __attribute__((ext_vector_type(4)));
typedef unsigned int uintx4 __attribute__((ext_vector_type(4)));

union V8 { short8 s; uintx4 u; };

__device__ __forceinline__ unsigned int bf16h(float f) {
    unsigned int b = __float_as_uint(f);
    return (b + 0x7FFFu + ((b >> 16) & 1u)) >> 16;   // RNE to bf16 (finite inputs)
}
__device__ __forceinline__ float bf16back(unsigned int h) {
    return __uint_as_float(h << 16);
}

__device__ __forceinline__ void merge_state(float& m, float& S, float& T,
                                            float m1, float S1, float T1) {
    const float mm = fminf(m, m1);
    const float e0 = __expf(ALPHA_F * (m  - mm));
    const float e1 = __expf(ALPHA_F * (m1 - mm));
    T = (T + (m - mm) * S) * e0 + (T1 + (m1 - mm) * S1) * e1;
    S = S * e0 + S1 * e1;
    m = mm;
}

__global__ __launch_bounds__(256, 2)
void softmin_mfma_kernel(const float* __restrict__ x,
                         const float* __restrict__ sh,
                         float* __restrict__ out) {
    // 16 regions (r=0..7 x half=hi/lo) of CPR shorts: cp[(2r+half)*CPR + e] = x_half[e + r]
    __shared__ __align__(16) short cp[16 * CPR];          // 34,048 B
    __shared__ __align__(16) float lds_xf[1056];          //  4,224 B (zeros 1024..1055)
    __shared__ __align__(16) float lds_sqw[984];          //  3,936 B (974.. = PAD_SQ)
    __shared__ __align__(16) short bl_lds[64 * 120];      // 15,360 B [lane][nt*16+ks*8]
    __shared__ float red_buf[4][NTILE][16][3];            //  5,376 B

    const int i    = blockIdx.x;
    const int tid  = threadIdx.x;
    const int lane = tid & 63;
    const int w    = tid >> 6;     // wave 0..3
    const int g    = lane >> 4;    // 0..3
    const int bcol = lane & 15;

    // ---- B prep: load shapelets, exact fp32 ssq, pack bf16 hi/lo fragments ----
    // B[kappa][n] frag: lane holds kappa = l0 + 8g + i (i=0..7), n = nt*16 + bcol.
    short8 bh[NTILE][2];
    float  ssqv[NTILE];
    #pragma unroll
    for (int nt = 0; nt < NTILE; ++nt) {
        const int n = nt * 16 + bcol;
        float sv[16];
        #pragma unroll
        for (int e = 0; e < 16; ++e) sv[e] = 0.f;
        if (n < K_SH) {
            const float* srow = sh + n * L_SH;
            const float2* p0 = (const float2*)(srow + 8 * g);        // kappa 8g..8g+7 (<32)
            #pragma unroll
            for (int q = 0; q < 4; ++q) { float2 v = p0[q]; sv[2*q] = v.x; sv[2*q+1] = v.y; }
            if (g < 2) {                                             // kappa 32+8g..+7 (<48)
                const float2* p1 = (const float2*)(srow + 32 + 8 * g);
                #pragma unroll
                for (int q = 0; q < 4; ++q) { float2 v = p1[q]; sv[8+2*q] = v.x; sv[9+2*q] = v.y; }
            } else if (g == 2) {                                     // kappa 48,49 real
                float2 v = *(const float2*)(srow + 48);
                sv[8] = v.x; sv[9] = v.y;
            }                                                        // g==3: all >=50 -> 0
        }
        float sq = 0.f;
        #pragma unroll
        for (int e = 0; e < 16; ++e) sq = fmaf(sv[e], sv[e], sq);
        sq += __shfl_xor(sq, 16);        // 4 g-groups hold disjoint kappa slices
        sq += __shfl_xor(sq, 32);
        ssqv[nt] = sq;

        unsigned int hb[16];
        #pragma unroll
        for (int e = 0; e < 16; ++e) hb[e] = bf16h(sv[e]);
        V8 h0, h1;
        h0.u = uintx4{hb[0]|(hb[1]<<16),  hb[2]|(hb[3]<<16),  hb[4]|(hb[5]<<16),  hb[6]|(hb[7]<<16)};
        h1.u = uintx4{hb[8]|(hb[9]<<16),  hb[10]|(hb[11]<<16),hb[12]|(hb[13]<<16),hb[14]|(hb[15]<<16)};
        bh[nt][0] = h0.s; bh[nt][1] = h1.s;

        if (tid < 64) {   // lo frags are lane-determined: wave 0 writes for all
            unsigned int lb[16];
            #pragma unroll
            for (int e = 0; e < 16; ++e) lb[e] = bf16h(sv[e] - bf16back(hb[e]));
            *(uintx4*)&bl_lds[lane*120 + nt*16] =
                uintx4{lb[0]|(lb[1]<<16),  lb[2]|(lb[3]<<16),  lb[4]|(lb[5]<<16),  lb[6]|(lb[7]<<16)};
            *(uintx4*)&bl_lds[lane*120 + nt*16 + 8] =
                uintx4{lb[8]|(lb[9]<<16),  lb[10]|(lb[11]<<16),lb[12]|(lb[13]<<16),lb[14]|(lb[15]<<16)};
        }
    }

    // ---- stage x row (f32) into LDS, zero-pad to 1056 ----
    {
        const float4* gx = (const float4*)(x + (size_t)i * Q_LEN);
        float4* lx = (float4*)lds_xf;
        lx[tid] = gx[tid];                                  // 256 * 4 = 1024
        if (tid < 8) lx[256 + tid] = make_float4(0.f, 0.f, 0.f, 0.f);
    }
    __syncthreads();

    // ---- sq_win (exact-ish fp32, sliding within groups of 4) ----
    if (tid < 246) {
        const float4* xf4 = (const float4*)lds_xf;
        float r0, r1, r2, r3;
        if (tid < 244) {
            float v[56];
            #pragma unroll
            for (int q = 0; q < 14; ++q) {
                float4 a = xf4[tid + q];
                v[4*q] = a.x; v[4*q+1] = a.y; v[4*q+2] = a.z; v[4*q+3] = a.w;
            }
            float s0 = 0.f;
            #pragma unroll
            for (int l = 0; l < L_SH; ++l) s0 = fmaf(v[l], v[l], s0);
            float s1 = fmaf(v[50], v[50], s0 - v[0]*v[0]);
            float s2 = fmaf(v[51], v[51], s1 - v[1]*v[1]);
            float s3 = fmaf(v[52], v[52], s2 - v[2]*v[2]);
            r0 = s0; r1 = s1; r2 = s2; r3 = s3;
            if (4*tid + 2 >= J_WIN) r2 = PAD_SQ;            // j = 974
            if (4*tid + 3 >= J_WIN) r3 = PAD_SQ;            // j = 975
        } else {
            r0 = r1 = r2 = r3 = PAD_SQ;                     // j 976..983
        }
        *(float4*)&lds_sqw[4*tid] = make_float4(r0, r1, r2, r3);
    }

    // ---- base bf16 hi/lo arrays (copy r=0) ----
    if (tid < 132) {
        const float4* xf4 = (const float4*)lds_xf;
        float4 a = xf4[2*tid], b = xf4[2*tid + 1];
        float xv[8] = {a.x, a.y, a.z, a.w, b.x, b.y, b.z, b.w};
        unsigned int hh[8], rr[8];
        #pragma unroll
        for (int e = 0; e < 8; ++e) {
            hh[e] = bf16h(xv[e]);
            rr[e] = bf16h(xv[e] - bf16back(hh[e]));
        }
        *(uintx4*)&cp[8*tid] =
            uintx4{hh[0]|(hh[1]<<16), hh[2]|(hh[3]<<16), hh[4]|(hh[5]<<16), hh[6]|(hh[7]<<16)};
        *(uintx4*)&cp[CPR + 8*tid] =
            uintx4{rr[0]|(rr[1]<<16), rr[2]|(rr[3]<<16), rr[4]|(rr[5]<<16), rr[6]|(rr[7]<<16)};
    }
    __syncthreads();

    // ---- shifted copies r=1..7 via aligned reads + 16-bit funnel shifts ----
    for (int un = tid; un < 262; un += 256) {                // 131 blocks x 2 halves
        const int half = un & 1, blk = un >> 1;
        const uintx4 A  = *(const uintx4*)&cp[half*CPR + 8*blk];
        const uintx4 B4 = *(const uintx4*)&cp[half*CPR + 8*blk + 8];
        unsigned int s[8] = {A[0], A[1], A[2], A[3], B4[0], B4[1], B4[2], B4[3]};
        #pragma unroll
        for (int r = 1; r < 8; ++r) {
            const int p = r >> 1;
            unsigned int o[4];
            if ((r & 1) == 0) {
                #pragma unroll
                for (int e = 0; e < 4; ++e) o[e] = s[p + e];
            } else {
                #pragma unroll
                for (int e = 0; e < 4; ++e) o[e] = (s[p + e] >> 16) | (s[p + e + 1] << 16);
            }
            *(uintx4*)&cp[(2*r + half)*CPR + 8*blk] = uintx4{o[0], o[1], o[2], o[3]};
        }
    }
    __syncthreads();

    // ---- main loop: per wave, M-tiles mt = w, w+4, ... ----
    // A frag elem i <-> x[j0 + (lane&15) + l0 + 8g + i]; start == lane (mod 8)
    // -> copy r = lane&7 at 8-aligned elem (j0 + l0 + 8*((lane>>3)&1) + 8g).
    const int r7       = lane & 7;
    const int lane_off = 8 * ((lane >> 3) & 1) + 8 * g;
    const int abase0   = (2 * r7) * CPR + lane_off;

    float stM[NTILE], stS[NTILE], stT[NTILE];
    #pragma unroll
    for (int nt = 0; nt < NTILE; ++nt) { stM[nt] = 1e30f; stS[nt] = 0.f; stT[nt] = 0.f; }

    for (int mt = w; mt < MTILES; mt += 4) {
        const int j0 = mt << 4;
        const int ae = abase0 + j0;
        const short8 ah0 = *(const short8*)&cp[ae];                // hi, kappa 0..31
        const short8 ah1 = *(const short8*)&cp[ae + 32];           // hi, kappa 32..63
        const short8 al0 = *(const short8*)&cp[ae + CPR];          // lo, kappa 0..31
        const short8 al1 = *(const short8*)&cp[ae + CPR + 32];     // lo, kappa 32..63
        const float4 sqv = *(const float4*)&lds_sqw[j0 + 4 * g];
        const float b0 = sqv.x * RINV_L, b1 = sqv.y * RINV_L,
                    b2 = sqv.z * RINV_L, b3 = sqv.w * RINV_L;

        #pragma unroll
        for (int nt = 0; nt < NTILE; ++nt) {
            const short8 bl0 = *(const short8*)&bl_lds[lane*120 + nt*16];
            const short8 bl1 = *(const short8*)&bl_lds[lane*120 + nt*16 + 8];
            f32x4 acc = {0.f, 0.f, 0.f, 0.f};
            acc = __builtin_amdgcn_mfma_f32_16x16x32_bf16(ah0, bh[nt][0], acc, 0, 0, 0);
            acc = __builtin_amdgcn_mfma_f32_16x16x32_bf16(ah1, bh[nt][1], acc, 0, 0, 0);
            acc = __builtin_amdgcn_mfma_f32_16x16x32_bf16(al0, bh[nt][0], acc, 0, 0, 0);
            acc = __builtin_amdgcn_mfma_f32_16x16x32_bf16(al1, bh[nt][1], acc, 0, 0, 0);
            acc = __builtin_amdgcn_mfma_f32_16x16x32_bf16(ah0, bl0,       acc, 0, 0, 0);
            acc = __builtin_amdgcn_mfma_f32_16x16x32_bf16(ah1, bl1,       acc, 0, 0, 0);

            const float tb = ssqv[nt] * RINV_L;
            const float dv0 = fmaf(acc[0], -2.f * RINV_L, tb + b0);
            const float dv1 = fmaf(acc[1], -2.f * RINV_L, tb + b1);
            const float dv2 = fmaf(acc[2], -2.f * RINV_L, tb + b2);
            const float dv3 = fmaf(acc[3], -2.f * RINV_L, tb + b3);
            const float cmin = fminf(fminf(dv0, dv1), fminf(dv2, dv3));
            if (cmin < stM[nt] + SKIP_T) {
                float m2 = stM[nt], S2 = stS[nt], T2 = stT[nt];
                const float nm = fminf(m2, cmin);
                const float sc = __expf(ALPHA_F * (m2 - nm));
                T2 = (T2 + (m2 - nm) * S2) * sc;
                S2 = S2 * sc;
                m2 = nm;
                { const float t = dv0 - m2; const float wg = __expf(ALPHA_F * t); S2 += wg; T2 = fmaf(t, wg, T2); }
                { const float t = dv1 - m2; const float wg = __expf(ALPHA_F * t); S2 += wg; T2 = fmaf(t, wg, T2); }
                { const float t = dv2 - m2; const float wg = __expf(ALPHA_F * t); S2 += wg; T2 = fmaf(t, wg, T2); }
                { const float t = dv3 - m2; const float wg = __expf(ALPHA_F * t); S2 += wg; T2 = fmaf(t, wg, T2); }
                stM[nt] = m2; stS[nt] = S2; stT[nt] = T2;
            }
        }
    }

    // ---- butterfly across the 4 row-groups (lanes differing in bits 4,5) ----
    #pragma unroll
    for (int nt = 0; nt < NTILE; ++nt) {
        float m = stM[nt], S = stS[nt], T = stT[nt];
        #pragma unroll
        for (int msk = 16; msk <= 32; msk <<= 1) {
            const float m1 = __shfl_xor(m, msk);
            const float S1 = __shfl_xor(S, msk);
            const float T1 = __shfl_xor(T, msk);
            merge_state(m, S, T, m1, S1, T1);
        }
        if (lane < 16) {
            red_buf[w][nt][lane][0] = m;
            red_buf[w][nt][lane][1] = S;
            red_buf[w][nt][lane][2] = T;
        }
    }
    __syncthreads();

    // ---- cross-wave merge + write ----
    if (tid < NTILE * 16) {
        const int nt = tid >> 4, kk = tid & 15;
        float m = red_buf[0][nt][kk][0], S = red_buf[0][nt][kk][1], T = red_buf[0][nt][kk][2];
        #pragma unroll
        for (int ww = 1; ww < 4; ++ww)
            merge_state(m, S, T, red_buf[ww][nt][kk][0], red_buf[ww][nt][kk][1], red_buf[ww][nt][kk][2]);
        const int k = nt * 16 + kk;
        if (k < K_SH) out[(size_t)i * K_SH + k] = T / S;
    }
}

extern "C" void kernel_launch(void* const* d_in, const int* in_sizes, int n_in,
                              void* d_out, int out_size, void* d_ws, size_t ws_size,
                              hipStream_t stream) {
    const float* x  = (const float*)d_in[0];   // (512, 1024) f32
    const float* sh = (const float*)d_in[1];   // (100, 50)  f32
    float* out = (float*)d_out;                // (512, 100) f32

    softmin_mfma_kernel<<<N_SEQ, 256, 0, stream>>>(x, sh, out);
}